// Round 5
// baseline (1641.190 us; speedup 1.0000x reference)
//
#include <hip/hip_runtime.h>

#define B_SZ 128
#define T_SZ 512
#define D_SZ 128
#define H_SZ 512

#define NG 8    // batch groups
#define GB 16   // batch rows per group
#define NS 4    // column slices (blocks per group)
#define SN 128  // columns per slice

typedef _Float16 f16;
typedef _Float16 f16x8 __attribute__((ext_vector_type(8)));
typedef _Float16 f16x4 __attribute__((ext_vector_type(4)));
typedef float f32x4 __attribute__((ext_vector_type(4)));

// ---------------- W_in transpose ----------------
__global__ __launch_bounds__(256) void transpose_k(const float* __restrict__ in,
                                                   float* __restrict__ out,
                                                   int R, int C) {
  __shared__ float tile[32][33];
  int c0 = blockIdx.x * 32, r0 = blockIdx.y * 32;
  int tx = threadIdx.x & 31, ty = threadIdx.x >> 5;
  for (int i = ty; i < 32; i += 8)
    tile[i][tx] = in[(size_t)(r0 + i) * C + (c0 + tx)];
  __syncthreads();
  for (int i = ty; i < 32; i += 8)
    out[(size_t)(c0 + i) * R + (r0 + tx)] = tile[tx][i];
}

// ---------------- x_in = x @ W_in^T + b ----------------
__global__ __launch_bounds__(256) void input_proj_k(
    const float* __restrict__ x,     // [BT][128]
    const float* __restrict__ WTin,  // [128][512]
    const float* __restrict__ bias,  // [512]
    float* __restrict__ out)         // [BT][512]
{
  __shared__ float xs[32 * 128];
  const int tid = threadIdx.x;
  const size_t r0 = (size_t)blockIdx.x * 32;

  const float4* xg = (const float4*)(x + r0 * D_SZ);
  float4* xs4s = (float4*)xs;
#pragma unroll
  for (int i = 0; i < 4; ++i) xs4s[tid + i * 256] = xg[tid + i * 256];
  __syncthreads();

  const int q = tid & 127;
  const int rg = tid >> 7;
  const float4* W4 = (const float4*)WTin;
  const float4* xs4 = (const float4*)xs;

  float acc[16][4];
#pragma unroll
  for (int r = 0; r < 16; ++r)
#pragma unroll
    for (int c = 0; c < 4; ++c) acc[r][c] = 0.f;

  for (int k4 = 0; k4 < 32; ++k4) {
    float w[4][4];
#pragma unroll
    for (int kk = 0; kk < 4; ++kk) {
      float4 wv = W4[(size_t)(k4 * 4 + kk) * 128 + q];
      w[kk][0] = wv.x; w[kk][1] = wv.y; w[kk][2] = wv.z; w[kk][3] = wv.w;
    }
#pragma unroll
    for (int r = 0; r < 16; ++r) {
      float4 xv = xs4[(rg * 16 + r) * 32 + k4];
      float xk[4] = {xv.x, xv.y, xv.z, xv.w};
#pragma unroll
      for (int kk = 0; kk < 4; ++kk)
#pragma unroll
        for (int c = 0; c < 4; ++c)
          acc[r][c] = fmaf(xk[kk], w[kk][c], acc[r][c]);
    }
  }

  float4 bv = ((const float4*)bias)[q];
  float bb[4] = {bv.x, bv.y, bv.z, bv.w};
#pragma unroll
  for (int r = 0; r < 16; ++r) {
    float4 o;
    o.x = acc[r][0] + bb[0];
    o.y = acc[r][1] + bb[1];
    o.z = acc[r][2] + bb[2];
    o.w = acc[r][3] + bb[3];
    ((float4*)(out + (r0 + rg * 16 + r) * H_SZ))[q] = o;
  }
}

__device__ __forceinline__ float fast_tanh(float y) {
  float e = __expf(2.0f * y);
  return 1.0f - __fdividef(2.0f, e + 1.0f);
}

// ---------------- recurrence ----------------
// 32 blocks x 256 threads (4 waves). Each wave owns TWO 16-col j-tiles
// (afrag = 128 VGPR), so per-CU LDS B-reads halve vs 8-wave config.
// Cross-block exchange: relaxed AGENT-scope (sc1, LLC) 8B atomics on a
// depth-2 f16 ring; handshake = one-shot flag store + 3 parallel polls
// (sequential non-exclusive ifs -> wave issues store before spinning).
__global__ __launch_bounds__(256) void ltc_rec_mfma(
    float* __restrict__ seq,        // [B][T][H]  in: x_in, out: h_seq
    float* __restrict__ h_last,     // [B][H]
    const float* __restrict__ hin,  // [B][H]
    const float* __restrict__ tau,  // [B]
    const float* __restrict__ Wrec, // [H][H] row-major
    int* __restrict__ flags,        // [NG][NS][T] one-shot step flags
    f16* __restrict__ ex)           // [2][NG][NS][GB][SN] exchange ring
{
  __shared__ f16 hs[2][GB * H_SZ];  // double-buffered, XOR-swizzled, 2x16KB

  const int tid = threadIdx.x;
  const int g = blockIdx.x & 7;
  const int slice = blockIdx.x >> 3;
  const int w = tid >> 6;          // wave 0..3
  const int l = tid & 63;
  const int m = l & 15;            // batch-in-group (MFMA col)
  const int kg = l >> 4;           // 0..3
  const int jt0 = slice * SN + w * 32;  // first j-tile base (global col)
  const int b = g * GB + m;

  // one-time: A-fragments = W_rec rows (f16), 2 tiles x 16 frags = 128 VGPR
  f16x8 afrag[2][16];
#pragma unroll
  for (int t = 0; t < 2; ++t) {
    const float* wr = Wrec + (size_t)(jt0 + t * 16 + m) * H_SZ;
#pragma unroll
    for (int f = 0; f < 16; ++f) {
      const int k0 = f * 32 + kg * 8;
      float4 u0 = *(const float4*)(wr + k0);
      float4 u1 = *(const float4*)(wr + k0 + 4);
      f16x8 a;
      a[0] = (f16)u0.x; a[1] = (f16)u0.y; a[2] = (f16)u0.z; a[3] = (f16)u0.w;
      a[4] = (f16)u1.x; a[5] = (f16)u1.y; a[6] = (f16)u1.z; a[7] = (f16)u1.w;
      afrag[t][f] = a;
    }
  }

  float hreg[2][4];
#pragma unroll
  for (int t = 0; t < 2; ++t) {
    float4 h0 = *(const float4*)(hin + (size_t)b * H_SZ + jt0 + t * 16 + kg * 4);
    hreg[t][0] = h0.x; hreg[t][1] = h0.y; hreg[t][2] = h0.z; hreg[t][3] = h0.w;
  }
  const float itau = 1.0f / tau[b];

  // init: full h_0 into hs[0] as f16 (each thread: rows mr, mr+8)
  {
    const int mr = tid >> 5;         // 0..7
    const int c4 = (tid & 31) * 4;
#pragma unroll
    for (int rr = 0; rr < 2; ++rr) {
      const int row = mr + rr * 8;
#pragma unroll
      for (int p = 0; p < 4; ++p) {
        const int col = p * SN + c4;
        float4 v = *(const float4*)(hin + (size_t)(g * GB + row) * H_SZ + col);
        const int e = (row * H_SZ + col) ^ ((row & 7) << 3);
        f16x4 hf;
        hf[0] = (f16)v.x; hf[1] = (f16)v.y; hf[2] = (f16)v.z; hf[3] = (f16)v.w;
        *(f16x4*)&hs[0][e] = hf;
      }
    }
  }
  __syncthreads();

  const int gmr = tid >> 5;
  const int gc4 = (tid & 31) * 4;

  float* seqp = seq + (size_t)b * T_SZ * H_SZ + jt0 + kg * 4;
  float4 xin0 = *(const float4*)seqp;
  float4 xin1 = *(const float4*)(seqp + 16);

  const size_t EXB = (size_t)GB * SN;  // 2048 f16 per (ring,g,slice)
  const int lcol = w * 32 + kg * 4;    // column within slice

  for (int s = 0; s < T_SZ; ++s) {
    const int cur = s & 1, nxt = cur ^ 1;

    // ---- recurrent GEMM: 2 j-tiles share each B-fragment ----
    f32x4 acc0 = {0.f, 0.f, 0.f, 0.f};
    f32x4 acc1 = {0.f, 0.f, 0.f, 0.f};
#pragma unroll
    for (int f = 0; f < 16; ++f) {
      const int e = (m * H_SZ + f * 32 + kg * 8) ^ ((m & 7) << 3);
      f16x8 bfrag = *(const f16x8*)&hs[cur][e];
      acc0 = __builtin_amdgcn_mfma_f32_16x16x32_f16(afrag[0][f], bfrag, acc0, 0, 0, 0);
      acc1 = __builtin_amdgcn_mfma_f32_16x16x32_f16(afrag[1][f], bfrag, acc1, 0, 0, 0);
    }

    // ---- epilogue (both tiles) ----
    float4 hv0, hv1;
    hv0.x = fmaf(fast_tanh(xin0.x + acc0[0]) - hreg[0][0], itau, hreg[0][0]);
    hv0.y = fmaf(fast_tanh(xin0.y + acc0[1]) - hreg[0][1], itau, hreg[0][1]);
    hv0.z = fmaf(fast_tanh(xin0.z + acc0[2]) - hreg[0][2], itau, hreg[0][2]);
    hv0.w = fmaf(fast_tanh(xin0.w + acc0[3]) - hreg[0][3], itau, hreg[0][3]);
    hv1.x = fmaf(fast_tanh(xin1.x + acc1[0]) - hreg[1][0], itau, hreg[1][0]);
    hv1.y = fmaf(fast_tanh(xin1.y + acc1[1]) - hreg[1][1], itau, hreg[1][1]);
    hv1.z = fmaf(fast_tanh(xin1.z + acc1[2]) - hreg[1][2], itau, hreg[1][2]);
    hv1.w = fmaf(fast_tanh(xin1.w + acc1[3]) - hreg[1][3], itau, hreg[1][3]);
    hreg[0][0] = hv0.x; hreg[0][1] = hv0.y; hreg[0][2] = hv0.z; hreg[0][3] = hv0.w;
    hreg[1][0] = hv1.x; hreg[1][1] = hv1.y; hreg[1][2] = hv1.z; hreg[1][3] = hv1.w;

    f16x4 hf0, hf1;
    hf0[0] = (f16)hv0.x; hf0[1] = (f16)hv0.y; hf0[2] = (f16)hv0.z; hf0[3] = (f16)hv0.w;
    hf1[0] = (f16)hv1.x; hf1[1] = (f16)hv1.y; hf1[2] = (f16)hv1.z; hf1[3] = (f16)hv1.w;

    // own slices into next LDS buffer
    {
      const int e0 = (m * H_SZ + jt0 + kg * 4) ^ ((m & 7) << 3);
      const int e1 = (m * H_SZ + jt0 + 16 + kg * 4) ^ ((m & 7) << 3);
      *(f16x4*)&hs[nxt][e0] = hf0;
      *(f16x4*)&hs[nxt][e1] = hf1;
    }
    // output stores: plain cached
    *(float4*)seqp = hv0;
    *(float4*)(seqp + 16) = hv1;
    seqp += H_SZ;
    // exchange publish: relaxed agent (sc1 -> LLC), 2x 8B
    {
      f16* exp_ = ex + ((size_t)(cur * NG + g) * NS + slice) * EXB + m * SN + lcol;
      __hip_atomic_store((unsigned long long*)exp_, __builtin_bit_cast(unsigned long long, hf0),
                         __ATOMIC_RELAXED, __HIP_MEMORY_SCOPE_AGENT);
      __hip_atomic_store((unsigned long long*)(exp_ + 16), __builtin_bit_cast(unsigned long long, hf1),
                         __ATOMIC_RELAXED, __HIP_MEMORY_SCOPE_AGENT);
    }

    __syncthreads();  // [1] implicit vmcnt(0): all sc1 stores LLC-acked

    // one-shot flag + 3 parallel polls. Sequential ifs (NOT else-if):
    // the wave issues the flag store before any lane starts spinning.
    if (tid == 0) {
      __hip_atomic_store(&flags[(size_t)(g * NS + slice) * T_SZ + s], 1,
                         __ATOMIC_RELAXED, __HIP_MEMORY_SCOPE_AGENT);
    }
    if (tid >= 1 && tid <= 3) {
      const int ps = (slice + tid) & 3;
      const int* pf = &flags[(size_t)(g * NS + ps) * T_SZ + s];
      while (__hip_atomic_load(pf, __ATOMIC_RELAXED, __HIP_MEMORY_SCOPE_AGENT) == 0) {}
    }
    __syncthreads();  // [2] peers' step-s data known visible at LLC

    // x_in prefetch for s+1
    xin0 = *(const float4*)seqp;
    xin1 = *(const float4*)(seqp + 16);

    // gather 3 peer slices (rows gmr, gmr+8) into hs[nxt]
#pragma unroll
    for (int rr = 0; rr < 2; ++rr) {
      const int row = gmr + rr * 8;
#pragma unroll
      for (int p = 0; p < 3; ++p) {
        const int ps = (slice + 1 + p) & 3;
        const f16* src = ex + ((size_t)(cur * NG + g) * NS + ps) * EXB + row * SN + gc4;
        unsigned long long bits =
            __hip_atomic_load((const unsigned long long*)src, __ATOMIC_RELAXED, __HIP_MEMORY_SCOPE_AGENT);
        f16x4 pv = __builtin_bit_cast(f16x4, bits);
        const int e = (row * H_SZ + ps * SN + gc4) ^ ((row & 7) << 3);
        *(f16x4*)&hs[nxt][e] = pv;
      }
    }
    __syncthreads();  // [3] hs[nxt] complete for step s+1
  }

  float4 hv;
  hv.x = hreg[0][0]; hv.y = hreg[0][1]; hv.z = hreg[0][2]; hv.w = hreg[0][3];
  *(float4*)(h_last + (size_t)b * H_SZ + jt0 + kg * 4) = hv;
  hv.x = hreg[1][0]; hv.y = hreg[1][1]; hv.z = hreg[1][2]; hv.w = hreg[1][3];
  *(float4*)(h_last + (size_t)b * H_SZ + jt0 + 16 + kg * 4) = hv;
}

extern "C" void kernel_launch(void* const* d_in, const int* in_sizes, int n_in,
                              void* d_out, int out_size, void* d_ws, size_t ws_size,
                              hipStream_t stream) {
  const float* x     = (const float*)d_in[0];
  const float* hin   = (const float*)d_in[1];
  const float* tau   = (const float*)d_in[2];
  const float* Win_w = (const float*)d_in[3];
  const float* Win_b = (const float*)d_in[4];
  const float* Wrec  = (const float*)d_in[5];

  float* out    = (float*)d_out;
  float* seq    = out;
  float* h_last = out + (size_t)B_SZ * T_SZ * H_SZ;

  int*   flags = (int*)d_ws;                                   // 64 KB
  f16*   ex    = (f16*)((char*)d_ws + 65536);                  // 256 KB
  float* WTin  = (float*)((char*)d_ws + 65536 + 262144);       // 256 KB

  hipMemsetAsync(flags, 0, NG * NS * T_SZ * sizeof(int), stream);

  dim3 blk(256);
  transpose_k<<<dim3(D_SZ / 32, H_SZ / 32), blk, 0, stream>>>(Win_w, WTin, H_SZ, D_SZ);
  input_proj_k<<<(B_SZ * T_SZ) / 32, blk, 0, stream>>>(x, WTin, Win_b, seq);
  ltc_rec_mfma<<<NG * NS, 256, 0, stream>>>(seq, h_last, hin, tau, Wrec, flags, ex);
}

// Round 6
// 1582.906 us; speedup vs baseline: 1.0368x; 1.0368x over previous
//
#include <hip/hip_runtime.h>

#define B_SZ 128
#define T_SZ 512
#define D_SZ 128
#define H_SZ 512

#define NG 8    // batch groups
#define GB 16   // batch rows per group
#define NS 4    // column slices (blocks per group)
#define SN 128  // columns per slice

typedef _Float16 f16;
typedef _Float16 f16x8 __attribute__((ext_vector_type(8)));
typedef _Float16 f16x4 __attribute__((ext_vector_type(4)));
typedef float f32x4 __attribute__((ext_vector_type(4)));
typedef unsigned long long ull;

// ---------------- W_in transpose ----------------
__global__ __launch_bounds__(256) void transpose_k(const float* __restrict__ in,
                                                   float* __restrict__ out,
                                                   int R, int C) {
  __shared__ float tile[32][33];
  int c0 = blockIdx.x * 32, r0 = blockIdx.y * 32;
  int tx = threadIdx.x & 31, ty = threadIdx.x >> 5;
  for (int i = ty; i < 32; i += 8)
    tile[i][tx] = in[(size_t)(r0 + i) * C + (c0 + tx)];
  __syncthreads();
  for (int i = ty; i < 32; i += 8)
    out[(size_t)(c0 + i) * R + (r0 + tx)] = tile[tx][i];
}

// ---------------- x_in = x @ W_in^T + b ----------------
__global__ __launch_bounds__(256) void input_proj_k(
    const float* __restrict__ x,     // [BT][128]
    const float* __restrict__ WTin,  // [128][512]
    const float* __restrict__ bias,  // [512]
    float* __restrict__ out)         // [BT][512]
{
  __shared__ float xs[32 * 128];
  const int tid = threadIdx.x;
  const size_t r0 = (size_t)blockIdx.x * 32;

  const float4* xg = (const float4*)(x + r0 * D_SZ);
  float4* xs4s = (float4*)xs;
#pragma unroll
  for (int i = 0; i < 4; ++i) xs4s[tid + i * 256] = xg[tid + i * 256];
  __syncthreads();

  const int q = tid & 127;
  const int rg = tid >> 7;
  const float4* W4 = (const float4*)WTin;
  const float4* xs4 = (const float4*)xs;

  float acc[16][4];
#pragma unroll
  for (int r = 0; r < 16; ++r)
#pragma unroll
    for (int c = 0; c < 4; ++c) acc[r][c] = 0.f;

  for (int k4 = 0; k4 < 32; ++k4) {
    float w[4][4];
#pragma unroll
    for (int kk = 0; kk < 4; ++kk) {
      float4 wv = W4[(size_t)(k4 * 4 + kk) * 128 + q];
      w[kk][0] = wv.x; w[kk][1] = wv.y; w[kk][2] = wv.z; w[kk][3] = wv.w;
    }
#pragma unroll
    for (int r = 0; r < 16; ++r) {
      float4 xv = xs4[(rg * 16 + r) * 32 + k4];
      float xk[4] = {xv.x, xv.y, xv.z, xv.w};
#pragma unroll
      for (int kk = 0; kk < 4; ++kk)
#pragma unroll
        for (int c = 0; c < 4; ++c)
          acc[r][c] = fmaf(xk[kk], w[kk][c], acc[r][c]);
    }
  }

  float4 bv = ((const float4*)bias)[q];
  float bb[4] = {bv.x, bv.y, bv.z, bv.w};
#pragma unroll
  for (int r = 0; r < 16; ++r) {
    float4 o;
    o.x = acc[r][0] + bb[0];
    o.y = acc[r][1] + bb[1];
    o.z = acc[r][2] + bb[2];
    o.w = acc[r][3] + bb[3];
    ((float4*)(out + (r0 + rg * 16 + r) * H_SZ))[q] = o;
  }
}

__device__ __forceinline__ float fast_tanh(float y) {
  float e = __expf(2.0f * y);
  return 1.0f - __fdividef(2.0f, e + 1.0f);
}

__device__ __forceinline__ ull ld_agent(const ull* p) {
  return __hip_atomic_load(p, __ATOMIC_RELAXED, __HIP_MEMORY_SCOPE_AGENT);
}

// ---------------- recurrence ----------------
// 32 blocks x 512 threads (8 waves, round-4 shape). Cross-block exchange via
// SELF-TAGGED 8B payloads on a depth-2 ring: LSB of f16[0] of each atomically
// stored word = generation parity (s>>1)&1. No flags, no drain-before-flag —
// one LLC RTT of exposed latency per step, one barrier per step.
// ABA-safe: a block publishes s+2 only after consuming all peers' s+1, which
// peers publish only after consuming s. Ring memset to 0xFF per launch
// (LSB=1 never false-matches the first parity-0 polls; slots are rewritten
// before the first parity-1 poll).
__global__ __launch_bounds__(512) void ltc_rec_mfma(
    float* __restrict__ seq,        // [B][T][H]  in: x_in, out: h_seq
    float* __restrict__ h_last,     // [B][H]
    const float* __restrict__ hin,  // [B][H]
    const float* __restrict__ tau,  // [B]
    const float* __restrict__ Wrec, // [H][H] row-major
    f16* __restrict__ ex)           // [2][NG][NS][GB][SN] exchange ring
{
  __shared__ f16 hs[2][GB * H_SZ];  // double-buffered, XOR-swizzled, 2x16KB

  const int tid = threadIdx.x;
  const int g = blockIdx.x & 7;
  const int slice = blockIdx.x >> 3;
  const int w = tid >> 6;          // wave 0..7
  const int l = tid & 63;
  const int m = l & 15;            // batch-in-group (MFMA col)
  const int kg = l >> 4;           // 0..3
  const int jt = slice * SN + w * 16;
  const int j0 = jt + kg * 4;
  const int b = g * GB + m;

  // one-time: A-fragments = W_rec rows (f16)
  f16x8 afrag[16];
  {
    const float* wr = Wrec + (size_t)(jt + m) * H_SZ;
#pragma unroll
    for (int f = 0; f < 16; ++f) {
      const int k0 = f * 32 + kg * 8;
      float4 u0 = *(const float4*)(wr + k0);
      float4 u1 = *(const float4*)(wr + k0 + 4);
      f16x8 a;
      a[0] = (f16)u0.x; a[1] = (f16)u0.y; a[2] = (f16)u0.z; a[3] = (f16)u0.w;
      a[4] = (f16)u1.x; a[5] = (f16)u1.y; a[6] = (f16)u1.z; a[7] = (f16)u1.w;
      afrag[f] = a;
    }
  }

  float hreg[4];
  {
    float4 h0 = *(const float4*)(hin + (size_t)b * H_SZ + j0);
    hreg[0] = h0.x; hreg[1] = h0.y; hreg[2] = h0.z; hreg[3] = h0.w;
  }
  const float itau = 1.0f / tau[b];

  // init: full h_0 into hs[0] as f16
  {
    const int mr = tid >> 5;         // 0..15
    const int c4 = (tid & 31) * 4;
#pragma unroll
    for (int p = 0; p < 4; ++p) {
      const int col = p * SN + c4;
      float4 v = *(const float4*)(hin + (size_t)(g * GB + mr) * H_SZ + col);
      const int e = (mr * H_SZ + col) ^ ((mr & 7) << 3);
      f16x4 hf;
      hf[0] = (f16)v.x; hf[1] = (f16)v.y; hf[2] = (f16)v.z; hf[3] = (f16)v.w;
      *(f16x4*)&hs[0][e] = hf;
    }
  }
  __syncthreads();

  // exchange addressing (ull units); slot-1 offset added per step
  const size_t EXB = (size_t)GB * SN;              // 2048 f16
  const size_t RING_ULL = (size_t)NG * NS * EXB / 4;  // 16384 ull per slot
  ull* pub0 = (ull*)(ex + ((size_t)g * NS + slice) * EXB + (size_t)m * SN + (w * 16 + kg * 4));

  const int gmr = tid >> 5;
  const int gc4 = (tid & 31) * 4;
  const int psa = (slice + 1) & 3, psb = (slice + 2) & 3, psc = (slice + 3) & 3;
  const ull* ga0 = (const ull*)(ex + ((size_t)g * NS + psa) * EXB + (size_t)gmr * SN + gc4);
  const ull* gb0 = (const ull*)(ex + ((size_t)g * NS + psb) * EXB + (size_t)gmr * SN + gc4);
  const ull* gc0 = (const ull*)(ex + ((size_t)g * NS + psc) * EXB + (size_t)gmr * SN + gc4);
  const int ea = (gmr * H_SZ + psa * SN + gc4) ^ ((gmr & 7) << 3);
  const int eb = (gmr * H_SZ + psb * SN + gc4) ^ ((gmr & 7) << 3);
  const int ec = (gmr * H_SZ + psc * SN + gc4) ^ ((gmr & 7) << 3);
  const int eown = (m * H_SZ + j0) ^ ((m & 7) << 3);

  float* seqp = seq + (size_t)b * T_SZ * H_SZ + j0;
  float4 xin = *(const float4*)seqp;  // step-0 x_in prefetch

  for (int s = 0; s < T_SZ; ++s) {
    const int cur = s & 1, nxt = cur ^ 1;
    const ull ptag = (ull)((s >> 1) & 1);
    const size_t roff = cur ? RING_ULL : 0;

    // ---- recurrent GEMM tile: acc[j=j0+r][m] over K=512 ----
    f32x4 acc0 = {0.f, 0.f, 0.f, 0.f};
    f32x4 acc1 = {0.f, 0.f, 0.f, 0.f};
#pragma unroll
    for (int f = 0; f < 8; ++f) {
      const int e = (m * H_SZ + f * 32 + kg * 8) ^ ((m & 7) << 3);
      acc0 = __builtin_amdgcn_mfma_f32_16x16x32_f16(afrag[f], *(const f16x8*)&hs[cur][e], acc0, 0, 0, 0);
    }
#pragma unroll
    for (int f = 8; f < 16; ++f) {
      const int e = (m * H_SZ + f * 32 + kg * 8) ^ ((m & 7) << 3);
      acc1 = __builtin_amdgcn_mfma_f32_16x16x32_f16(afrag[f], *(const f16x8*)&hs[cur][e], acc1, 0, 0, 0);
    }
    f32x4 acc = acc0 + acc1;

    // ---- epilogue ----
    float4 hv;
    hv.x = fmaf(fast_tanh(xin.x + acc[0]) - hreg[0], itau, hreg[0]);
    hv.y = fmaf(fast_tanh(xin.y + acc[1]) - hreg[1], itau, hreg[1]);
    hv.z = fmaf(fast_tanh(xin.z + acc[2]) - hreg[2], itau, hreg[2]);
    hv.w = fmaf(fast_tanh(xin.w + acc[3]) - hreg[3], itau, hreg[3]);
    hreg[0] = hv.x; hreg[1] = hv.y; hreg[2] = hv.z; hreg[3] = hv.w;

    f16x4 hf;
    hf[0] = (f16)hv.x; hf[1] = (f16)hv.y; hf[2] = (f16)hv.z; hf[3] = (f16)hv.w;

    // ---- publish FIRST (critical path): tagged word, relaxed sc1 ----
    ull bits = __builtin_bit_cast(ull, hf);
    bits = (bits & ~1ULL) | ptag;
    __hip_atomic_store(pub0 + roff, bits, __ATOMIC_RELAXED, __HIP_MEMORY_SCOPE_AGENT);

    // ---- issue gather loads (overlap with local work below) ----
    ull w0 = ld_agent(ga0 + roff);
    ull w1 = ld_agent(gb0 + roff);
    ull w2 = ld_agent(gc0 + roff);

    // ---- local work under the loads ----
    *(f16x4*)&hs[nxt][eown] = hf;       // own slice (untagged, exact f16)
    *(float4*)seqp = hv;                // h_seq output (plain cached)
    seqp += H_SZ;
    xin = *(const float4*)seqp;         // x_in prefetch for s+1

    // ---- poll tags; reload only stale words ----
    while ((w0 & 1ULL) != ptag) w0 = ld_agent(ga0 + roff);
    while ((w1 & 1ULL) != ptag) w1 = ld_agent(gb0 + roff);
    while ((w2 & 1ULL) != ptag) w2 = ld_agent(gc0 + roff);

    // ---- peer slices into hs[nxt] ----
    *(f16x4*)&hs[nxt][ea] = __builtin_bit_cast(f16x4, w0);
    *(f16x4*)&hs[nxt][eb] = __builtin_bit_cast(f16x4, w1);
    *(f16x4*)&hs[nxt][ec] = __builtin_bit_cast(f16x4, w2);

    __syncthreads();  // hs[nxt] complete; also orders WAR on hs[cur]
  }

  float4 hv;
  hv.x = hreg[0]; hv.y = hreg[1]; hv.z = hreg[2]; hv.w = hreg[3];
  *(float4*)(h_last + (size_t)b * H_SZ + j0) = hv;
}

extern "C" void kernel_launch(void* const* d_in, const int* in_sizes, int n_in,
                              void* d_out, int out_size, void* d_ws, size_t ws_size,
                              hipStream_t stream) {
  const float* x     = (const float*)d_in[0];
  const float* hin   = (const float*)d_in[1];
  const float* tau   = (const float*)d_in[2];
  const float* Win_w = (const float*)d_in[3];
  const float* Win_b = (const float*)d_in[4];
  const float* Wrec  = (const float*)d_in[5];

  float* out    = (float*)d_out;
  float* seq    = out;
  float* h_last = out + (size_t)B_SZ * T_SZ * H_SZ;

  f16*   ex   = (f16*)d_ws;                           // 256 KB (2-slot ring)
  float* WTin = (float*)((char*)d_ws + 262144);       // 256 KB

  // ring to 0xFF: f16[0]=0xFFFF (LSB=1) never false-matches first parity-0
  // polls; every slot is producer-overwritten before its first parity-1 poll.
  hipMemsetAsync(ex, 0xFF, 2 * NG * NS * GB * SN * sizeof(f16), stream);

  dim3 blk(256);
  transpose_k<<<dim3(D_SZ / 32, H_SZ / 32), blk, 0, stream>>>(Win_w, WTin, H_SZ, D_SZ);
  input_proj_k<<<(B_SZ * T_SZ) / 32, blk, 0, stream>>>(x, WTin, Win_b, seq);
  ltc_rec_mfma<<<NG * NS, 512, 0, stream>>>(seq, h_last, hin, tau, Wrec, ex);
}